// Round 20
// baseline (348.727 us; speedup 1.0000x reference)
//
#include <hip/hip_runtime.h>
#include <hip/hip_bf16.h>
#include <stdint.h>

#define NB 4
#define NT 8192
#define ND 1024
#define NH 16
#define NHD 64
#define NK 64        // top-k
#define NM (NB*NT)   // 32768

typedef __attribute__((ext_vector_type(4))) float f32x4;
typedef __attribute__((ext_vector_type(8))) short s16x8;
typedef const void __attribute__((address_space(1)))* gas1_t;
typedef void __attribute__((address_space(3)))* las3_t;

__device__ __forceinline__ float bf2f(ushort u) {
  union { uint32_t i; float f; } v; v.i = ((uint32_t)u) << 16; return v.f;
}
__device__ __forceinline__ ushort f2bf(float f) {
  union { float f; uint32_t i; } v; v.f = f;
  uint32_t r = v.i + 0x7FFFu + ((v.i >> 16) & 1u);
  return (ushort)(r >> 16);
}
__device__ __forceinline__ uint32_t f2ord(uint32_t u) {
  return (u & 0x80000000u) ? ~u : (u | 0x80000000u);
}

// ---- convert weights to bf16; blocks 0..63 also compute u (split-bf16) ----
__global__ __launch_bounds__(256) void convert_w_kernel(
    const float* __restrict__ Wq, const float* __restrict__ Wk,
    const float* __restrict__ Wv, const float* __restrict__ Wo,
    const float* __restrict__ wscore,
    ushort* __restrict__ wqb, ushort* __restrict__ wkb,
    ushort* __restrict__ wvb, ushort* __restrict__ wob,
    ushort* __restrict__ uhi, ushort* __restrict__ ulo) {
  int i = blockIdx.x * 256 + threadIdx.x;   // grid covers exactly 1M
  wqb[i] = f2bf(Wq[i]); wkb[i] = f2bf(Wk[i]);
  wvb[i] = f2bf(Wv[i]); wob[i] = f2bf(Wo[i]);
  if (blockIdx.x < 64) {   // fused prep_u: u[h] = sum_d wscore[d]*Wk[h*64+d]
    int e = (blockIdx.x & 3) * 256 + threadIdx.x;
    int h = blockIdx.x >> 2;
    float acc = 0.f;
    #pragma unroll 8
    for (int d = 0; d < NHD; ++d) acc += wscore[d] * Wk[(size_t)(h*NHD + d)*ND + e];
    ushort hv = f2bf(acc);
    uhi[h*ND + e] = hv;
    ulo[h*ND + e] = f2bf(acc - bf2f(hv));
  }
}

// ---- x -> xb (bf16) fused with scores = x @ u^T via split-bf16 MFMA ----
__global__ __launch_bounds__(256) void prep_x_kernel(
    const float* __restrict__ x, const ushort* __restrict__ uhi,
    const ushort* __restrict__ ulo, ushort* __restrict__ xb,
    float* __restrict__ scores) {
  __shared__ __align__(16) ushort Ahi[32 * 128];
  __shared__ __align__(16) ushort Alo[32 * 128];
  __shared__ float red[4][2][16][17];
  int t = threadIdx.x, w = t >> 6, l = t & 63;
  int tok0 = blockIdx.x * 32;
  int srow = t >> 3;             // stage row 0..31
  int sg = (t & 7) * 2;          // stage granule base (2 granules of 8 bf16)
  int rs = l & 15, ks8 = (l >> 4) * 8;
  f32x4 acc[2];
  acc[0] = (f32x4){0.f,0.f,0.f,0.f};
  acc[1] = (f32x4){0.f,0.f,0.f,0.f};
  for (int kc = 0; kc < 8; ++kc) {
    int kb = kc * 128;
    {  // coalesced stage: x[tok0+srow][kb + sg*8 .. +16]
      const float* xr = x + (size_t)(tok0 + srow) * ND + kb + sg * 8;
      f32x4 v0 = *(const f32x4*)xr;
      f32x4 v1 = *(const f32x4*)(xr + 4);
      f32x4 v2 = *(const f32x4*)(xr + 8);
      f32x4 v3 = *(const f32x4*)(xr + 12);
      s16x8 hi0, lo0, hi1, lo1;
      #pragma unroll
      for (int j = 0; j < 4; ++j) {
        ushort h;
        h = f2bf(v0[j]); hi0[j]   = (short)h; lo0[j]   = (short)f2bf(v0[j] - bf2f(h));
        h = f2bf(v1[j]); hi0[4+j] = (short)h; lo0[4+j] = (short)f2bf(v1[j] - bf2f(h));
        h = f2bf(v2[j]); hi1[j]   = (short)h; lo1[j]   = (short)f2bf(v2[j] - bf2f(h));
        h = f2bf(v3[j]); hi1[4+j] = (short)h; lo1[4+j] = (short)f2bf(v3[j] - bf2f(h));
      }
      ushort* xo = xb + (size_t)(tok0 + srow) * ND + kb + sg * 8;
      *(s16x8*)xo = hi0;              // coalesced 32B/thread
      *(s16x8*)(xo + 8) = hi1;
      int p0 = (sg ^ (srow & 7)) * 8, p1 = ((sg + 1) ^ (srow & 7)) * 8;
      *(s16x8*)&Ahi[srow*128 + p0] = hi0;
      *(s16x8*)&Ahi[srow*128 + p1] = hi1;
      *(s16x8*)&Alo[srow*128 + p0] = lo0;
      *(s16x8*)&Alo[srow*128 + p1] = lo1;
    }
    __syncthreads();
    {  // wave w consumes cols [w*32, w*32+32) of this 128-col step
      s16x8 bh = *(const s16x8*)(uhi + rs * ND + kb + w * 32 + ks8);
      s16x8 bl = *(const s16x8*)(ulo + rs * ND + kb + w * 32 + ks8);
      int gl = w * 4 + (l >> 4);
      #pragma unroll
      for (int mi = 0; mi < 2; ++mi) {
        int row = mi * 16 + rs;
        int gp = (gl ^ (row & 7)) * 8;
        s16x8 ah = *(const s16x8*)&Ahi[row*128 + gp];
        s16x8 al = *(const s16x8*)&Alo[row*128 + gp];
        acc[mi] = __builtin_amdgcn_mfma_f32_16x16x32_bf16(ah, bh, acc[mi], 0, 0, 0);
        acc[mi] = __builtin_amdgcn_mfma_f32_16x16x32_bf16(al, bh, acc[mi], 0, 0, 0);
        acc[mi] = __builtin_amdgcn_mfma_f32_16x16x32_bf16(ah, bl, acc[mi], 0, 0, 0);
      }
    }
    __syncthreads();
  }
  #pragma unroll
  for (int mi = 0; mi < 2; ++mi)
    #pragma unroll
    for (int r = 0; r < 4; ++r)
      red[w][mi][(l >> 4) * 4 + r][l & 15] = acc[mi][r];
  __syncthreads();
  int boff = ((tok0 >> 13) << 4);
  int tt0 = tok0 & (NT - 1);
  #pragma unroll
  for (int it = 0; it < 2; ++it) {
    int tok = t & 31, h = (t >> 5) + it * 8;
    int mi = tok >> 4, row = tok & 15;
    float s = red[0][mi][row][h] + red[1][mi][row][h]
            + red[2][mi][row][h] + red[3][mi][row][h];
    scores[(size_t)(boff + h) * NT + tt0 + tok] = s;
  }
}

// ---- FUSED: top-64 radix-select (kid in LDS) + MFMA K/V projection ----
__global__ __launch_bounds__(256) void topsel_kv_kernel(
    const float* __restrict__ scores, const ushort* __restrict__ xb,
    const ushort* __restrict__ wkb, const ushort* __restrict__ wvb,
    ushort* __restrict__ ksp, ushort* __restrict__ vtsp) {
  int bh = blockIdx.x, t = threadIdx.x;
  int b = bh >> 4, h = bh & 15;
  __shared__ uint32_t keys[NT];      // 32 KiB
  __shared__ int hist[4096];         // 16 KiB
  __shared__ uint32_t ck[512];
  __shared__ int ci[512];
  __shared__ int chunksum[256];
  __shared__ int s_binB, s_c0;
  __shared__ int cnt_hi, cnt_cand;
  __shared__ int kid[64];
  __shared__ __align__(16) ushort Xs[64 * 128];     // 16 KiB
  __shared__ __align__(16) ushort Ws[2][64 * 128];  // 32 KiB

  // ---- phase 1: top-64 ----
  for (int i = t; i < 4096; i += 256) hist[i] = 0;
  if (t == 0) { cnt_hi = 0; cnt_cand = 0; }
  __syncthreads();
  const uint4* sg = (const uint4*)(scores + (size_t)bh * NT);
  for (int i = t; i < NT/4; i += 256) {
    uint4 v = sg[i];
    uint32_t k0 = f2ord(v.x), k1 = f2ord(v.y), k2 = f2ord(v.z), k3 = f2ord(v.w);
    keys[i*4+0] = k0; keys[i*4+1] = k1; keys[i*4+2] = k2; keys[i*4+3] = k3;
    atomicAdd(&hist[k0 >> 20], 1); atomicAdd(&hist[k1 >> 20], 1);
    atomicAdd(&hist[k2 >> 20], 1); atomicAdd(&hist[k3 >> 20], 1);
  }
  __syncthreads();
  {
    int hi = 4095 - t * 16;
    int s = 0;
    #pragma unroll
    for (int j = 0; j < 16; ++j) s += hist[hi - j];
    chunksum[t] = s;
  }
  __syncthreads();
  if (t == 0) {
    int cum = 0, c = 0;
    while (cum + chunksum[c] < NK) { cum += chunksum[c]; ++c; }
    int bin = 4095 - c * 16;
    while (cum + hist[bin] < NK) { cum += hist[bin]; --bin; }
    s_binB = bin; s_c0 = cum;
  }
  __syncthreads();
  int binB = s_binB, c0 = s_c0;
  for (int i = t; i < NT; i += 256) {
    int bb = keys[i] >> 20;
    if (bb > binB) {
      int p = atomicAdd(&cnt_hi, 1);
      kid[p] = i;
    } else if (bb == binB) {
      int p = atomicAdd(&cnt_cand, 1);
      if (p < 512) { ck[p] = keys[i]; ci[p] = i; }
    }
  }
  __syncthreads();
  int nc = cnt_cand; if (nc > 512) nc = 512;
  int need = NK - c0;
  for (int p = t; p < nc; p += 256) {
    uint32_t myk = ck[p]; int myi = ci[p];
    int rank = 0;
    for (int j = 0; j < nc; ++j) {
      uint32_t kj = ck[j];
      rank += (kj > myk || (kj == myk && ci[j] < myi)) ? 1 : 0;
    }
    if (rank < need) kid[c0 + rank] = myi;
  }

  // ---- phase 2: K_sp = X_sel @ Wk_h^T, V_sp^T likewise (MFMA) ----
  int w = t >> 6, l = t & 63;
  int sel = w >> 1, nb = (w & 1) * 32;
  f32x4 acc[4][2];
  #pragma unroll
  for (int mi = 0; mi < 4; ++mi)
    #pragma unroll
    for (int ni = 0; ni < 2; ++ni) acc[mi][ni] = (f32x4){0.f,0.f,0.f,0.f};
  int srow = t >> 2;             // 0..63
  int gj = (t & 3) * 4;          // granule base
  for (int kc = 0; kc < ND; kc += 128) {
    __syncthreads();
    const ushort* xr  = xb  + (size_t)(b*NT + kid[srow]) * ND + kc;
    const ushort* wkr = wkb + (size_t)(h*NHD + srow) * ND + kc;
    const ushort* wvr = wvb + (size_t)(h*NHD + srow) * ND + kc;
    #pragma unroll
    for (int j = 0; j < 4; ++j) {
      int p = ((gj + j) ^ (srow & 7)) * 8;
      *(uint4*)&Xs[srow*128 + p]    = *(const uint4*)(xr  + (gj + j) * 8);
      *(uint4*)&Ws[0][srow*128 + p] = *(const uint4*)(wkr + (gj + j) * 8);
      *(uint4*)&Ws[1][srow*128 + p] = *(const uint4*)(wvr + (gj + j) * 8);
    }
    __syncthreads();
    #pragma unroll
    for (int ks = 0; ks < 4; ++ks) {
      s16x8 bfr[2], afr[4];
      #pragma unroll
      for (int ni = 0; ni < 2; ++ni) {
        int row = nb + ni*16 + (l & 15);
        bfr[ni] = *(const s16x8*)&Ws[sel][row*128 + ((ks*4 + (l >> 4)) ^ (row & 7))*8];
      }
      #pragma unroll
      for (int mi = 0; mi < 4; ++mi) {
        int row = mi*16 + (l & 15);
        afr[mi] = *(const s16x8*)&Xs[row*128 + ((ks*4 + (l >> 4)) ^ (row & 7))*8];
      }
      #pragma unroll
      for (int mi = 0; mi < 4; ++mi)
        #pragma unroll
        for (int ni = 0; ni < 2; ++ni)
          acc[mi][ni] = __builtin_amdgcn_mfma_f32_16x16x32_bf16(
              afr[mi], bfr[ni], acc[mi][ni], 0, 0, 0);
    }
  }
  #pragma unroll
  for (int mi = 0; mi < 4; ++mi)
    #pragma unroll
    for (int ni = 0; ni < 2; ++ni) {
      int d = nb + ni*16 + (l & 15);
      int key0 = mi*16 + (l >> 4)*4;
      if (sel == 0) {
        #pragma unroll
        for (int r = 0; r < 4; ++r)
          ksp[((size_t)bh*NK + key0 + r)*NHD + d] = f2bf(acc[mi][ni][r]);
      } else {
        ushort4 o;
        o.x = f2bf(acc[mi][ni][0]); o.y = f2bf(acc[mi][ni][1]);
        o.z = f2bf(acc[mi][ni][2]); o.w = f2bf(acc[mi][ni][3]);
        *(ushort4*)&vtsp[((size_t)bh*NHD + d)*NK + key0] = o;
      }
    }
}

// ==== 256x256 GEMM (R11 8-phase). FUSE_ATTN=1: the epilogue runs the full
// attention for this block's 256 tokens x 4 heads (Q never touches HBM).
// After the K-loop the 128KB LDS is dead (all waves past the final barrier):
// per head-group hg (2 heads): dump acc cols [hg*128,+128) to a 64KB
// granule-swizzled bf16 Q tile, sync, then 8 waves = (head_local x token-
// quarter) run the R11 attn body (Q frags from LDS: row-pairs 2048B apart =
// same-bank 2-way = free; K/V from global, L2-resident), writing aout.
// Register ledger: written acc half + afr/bfr dead at attn time ->
// peak ~64 AGPR + ~178 VGPR < 256 (2 waves/SIMD budget).
template<int FUSE_ATTN>
__global__ __launch_bounds__(512, 2) void gemm8_kernel(
    const ushort* __restrict__ A, const ushort* __restrict__ Bw,
    void* __restrict__ Cout,
    const ushort* __restrict__ ksp, const ushort* __restrict__ vtsp) {
  __shared__ __align__(16) char lds[131072];
  const int t = threadIdx.x, wid = t >> 6, l = t & 63;
  const int wr = wid >> 2, wc = wid & 3;
  int bid = blockIdx.x;                  // nwg = 512 = 8 XCD * 64
  int wg = (bid & 7) * 64 + (bid >> 3);  // XCD swizzle (bijective, 512%8==0)
  int tm = wg >> 2, tn = wg & 3;
  const int K = 1024, N = 1024;
  const ushort* Ab = A + (size_t)tm * 256 * K;
  const ushort* Bb = Bw + (size_t)tn * 256 * K;
  const int skh  = ((l & 3) * 8) ^ (((l >> 5) & 1) << 4);  // pre-swizzled src k
  const int srow = l >> 2;
  const int lane_off = (l & 15) * 64 + ((((l >> 4) * 8) ^ (((l >> 3) & 1) << 4)) * 2);
  f32x4 acc[8][4];
  #pragma unroll
  for (int i = 0; i < 8; ++i)
    #pragma unroll
    for (int j = 0; j < 4; ++j) acc[i][j] = (f32x4){0.f, 0.f, 0.f, 0.f};
  s16x8 afr[4][2], bfr[2][2];

#define STG(gbase, matoff, half, ktile, buf) do { \
    const ushort* _s = (gbase) + (size_t)((half)*128 + wid*16 + srow) * K + (ktile)*64 + skh; \
    int _d = (buf)*65536 + (matoff) + ((half)*128 + wid*16)*64; \
    __builtin_amdgcn_global_load_lds((gas1_t)_s, (las3_t)(lds + _d), 16, 0, 0); \
    __builtin_amdgcn_global_load_lds((gas1_t)(_s + 32), (las3_t)(lds + _d + 16384), 16, 0, 0); \
  } while (0)

#define RD_A(mh, kh, buf) do { \
    _Pragma("unroll") \
    for (int mi = 0; mi < 4; ++mi) \
      afr[mi][kh] = *(const s16x8*)(lds + (buf)*65536 + (kh)*16384 + \
                      ((((mh)*2 + wr)*64 + mi*16))*64 + lane_off); \
  } while (0)

#define RD_B(nh, kh, buf) do { \
    _Pragma("unroll") \
    for (int ni = 0; ni < 2; ++ni) \
      bfr[ni][kh] = *(const s16x8*)(lds + (buf)*65536 + 32768 + (kh)*16384 + \
                      (((nh)*128 + wc*32 + ni*16))*64 + lane_off); \
  } while (0)

#define MMAQH(mh, nh, kh) do { \
    __builtin_amdgcn_s_setprio(1); \
    _Pragma("unroll") \
    for (int mi = 0; mi < 4; ++mi) \
      _Pragma("unroll") \
      for (int ni = 0; ni < 2; ++ni) \
        acc[(mh)*4+mi][(nh)*2+ni] = __builtin_amdgcn_mfma_f32_16x16x32_bf16( \
            afr[mi][kh], bfr[ni][kh], acc[(mh)*4+mi][(nh)*2+ni], 0, 0, 0); \
    __builtin_amdgcn_s_setprio(0); \
  } while (0)

#define LG0() do { asm volatile("s_waitcnt lgkmcnt(0)" ::: "memory"); \
                   __builtin_amdgcn_sched_barrier(0); } while (0)
#define ENDPH() do { __builtin_amdgcn_sched_barrier(0); \
                     __builtin_amdgcn_s_barrier(); } while (0)

#define TILE(kt, bc, bn) do { \
  LG0(); MMAQH(0,0,0); RD_A(0,1,bc); RD_B(0,1,bc); ENDPH(); \
  LG0(); MMAQH(0,0,1); RD_B(1,0,bc); \
  if ((kt)+1 < 16) STG(Bb,32768,0,(kt)+1,bn); ENDPH(); \
  LG0(); MMAQH(0,1,0); RD_B(1,1,bc); ENDPH(); \
  LG0(); MMAQH(0,1,1); RD_A(1,0,bc); \
  if ((kt)+2 < 16) STG(Ab,0,0,(kt)+2,bc); ENDPH(); \
  LG0(); MMAQH(1,1,0); RD_A(1,1,bc); ENDPH(); \
  LG0(); MMAQH(1,1,1); RD_B(0,0,bc); \
  if ((kt)+2 < 16) STG(Bb,32768,1,(kt)+2,bc); ENDPH(); \
  LG0(); MMAQH(1,0,0); RD_B(0,1,bc); ENDPH(); \
  LG0(); MMAQH(1,0,1); \
  if ((kt) < 14)       { asm volatile("s_waitcnt vmcnt(4)" ::: "memory"); } \
  else if ((kt) == 14) { asm volatile("s_waitcnt vmcnt(0)" ::: "memory"); } \
  __builtin_amdgcn_sched_barrier(0); \
  __builtin_amdgcn_s_barrier(); \
  if ((kt)+1 < 16) { RD_A(0,0,bn); RD_B(0,0,bn); } \
  if ((kt)+2 < 16) STG(Ab,0,1,(kt)+2,bc); \
} while (0)

  // prologue: t0 all 4 halves + t1 {A0,B1,A1}; B0(t1) arrives at ph2 of t0
  STG(Ab,0,0,0,0); STG(Bb,32768,0,0,0); STG(Ab,0,1,0,0); STG(Bb,32768,1,0,0);
  STG(Ab,0,0,1,1); STG(Bb,32768,1,1,1); STG(Ab,0,1,1,1);
  asm volatile("s_waitcnt vmcnt(6)" ::: "memory");   // t0's 8 loads done
  __builtin_amdgcn_s_barrier();
  RD_A(0,0,0); RD_B(0,0,0);                          // A0k0,B0k0 of t0

  for (int k2 = 0; k2 < 8; ++k2) {
    TILE(2*k2,     0, 1);
    TILE(2*k2 + 1, 1, 0);
  }
#undef TILE
#undef STG
#undef RD_A
#undef RD_B
#undef MMAQH
#undef LG0
#undef ENDPH

  if (!FUSE_ATTN) {
    // plain epilogue: f32 C, layout col=l&15, row=(l>>4)*4+r
    #pragma unroll
    for (int mi8 = 0; mi8 < 8; ++mi8) {
      int grow = tm*256 + (((mi8 >> 2)*2 + wr)*64) + (mi8 & 3)*16 + (l >> 4)*4;
      #pragma unroll
      for (int ni4 = 0; ni4 < 4; ++ni4) {
        int gcol = tn*256 + (ni4 >> 1)*128 + wc*32 + (ni4 & 1)*16 + (l & 15);
        #pragma unroll
        for (int r = 0; r < 4; ++r) {
          size_t off = (size_t)(grow + r) * N + gcol;
          ((float*)Cout)[off] = acc[mi8][ni4][r];
        }
      }
    }
  } else {
    // fused attention epilogue
    ushort* Qs = (ushort*)lds;               // 64 KiB: 256 rows x 128 cols
    ushort* Pl = (ushort*)(lds + 65536);     // 16 KiB: 8 waves x 1024
    ushort* ap = (ushort*)Cout;              // aout, token-major [32768][1024]
    const int hl = wid >> 2, tq = wid & 3;   // head-local, token-quarter
    #pragma unroll 1
    for (int hg = 0; hg < 2; ++hg) {
      // stage Q chunk (C cols hg*128..+128) into Qs, granule-swizzled
      #pragma unroll
      for (int mi8 = 0; mi8 < 8; ++mi8) {
        int lrow0 = ((mi8 >> 2)*2 + wr)*64 + (mi8 & 3)*16 + (l >> 4)*4;
        #pragma unroll
        for (int nj = 0; nj < 2; ++nj) {
          int ccol = wc*32 + nj*16 + (l & 15);
          int colg = ccol >> 3;
          #pragma unroll
          for (int r = 0; r < 4; ++r) {
            int lrow = lrow0 + r;
            Qs[lrow*128 + ((colg ^ (lrow & 7))*8) + (ccol & 7)] =
                f2bf(acc[mi8][hg*2 + nj][r]);
          }
        }
      }
      __syncthreads();
      int h = tn*4 + hg*2 + hl;
      int bh2 = ((tm*256) >> 13) * 16 + h;
      const ushort* kb = ksp + (size_t)bh2 * NK * NHD;
      const ushort* vb = vtsp + (size_t)bh2 * NHD * NK;
      s16x8 kf[2][4], vf[2][4];
      #pragma unroll
      for (int ks = 0; ks < 2; ++ks)
        #pragma unroll
        for (int ni = 0; ni < 4; ++ni) {
          kf[ks][ni] = *(const s16x8*)&kb[(size_t)(ni*16 + (l & 15))*NHD + ks*32 + (l >> 4)*8];
          vf[ks][ni] = *(const s16x8*)&vb[(size_t)(ni*16 + (l & 15))*NK + ks*32 + (l >> 4)*8];
        }
      #pragma unroll 1
      for (int mi = 0; mi < 4; ++mi) {
        int lr0 = tq*64 + mi*16;
        s16x8 af[2];
        #pragma unroll
        for (int ks = 0; ks < 2; ++ks) {
          int lrow = lr0 + (l & 15);
          int colg = hl*8 + ks*4 + (l >> 4);
          af[ks] = *(const s16x8*)&Qs[lrow*128 + ((colg ^ (lrow & 7))*8)];
        }
        f32x4 sc[4];
        #pragma unroll
        for (int ni = 0; ni < 4; ++ni) {
          f32x4 z; z[0]=0.f; z[1]=0.f; z[2]=0.f; z[3]=0.f;
          z = __builtin_amdgcn_mfma_f32_16x16x32_bf16(af[0], kf[0][ni], z, 0, 0, 0);
          sc[ni] = __builtin_amdgcn_mfma_f32_16x16x32_bf16(af[1], kf[1][ni], z, 0, 0, 0);
        }
        #pragma unroll
        for (int r = 0; r < 4; ++r) {
          float v0 = sc[0][r]*0.125f, v1 = sc[1][r]*0.125f;
          float v2 = sc[2][r]*0.125f, v3 = sc[3][r]*0.125f;
          float m = fmaxf(fmaxf(v0, v1), fmaxf(v2, v3));
          #pragma unroll
          for (int mm = 8; mm >= 1; mm >>= 1) m = fmaxf(m, __shfl_xor(m, mm, 64));
          float e0 = __expf(v0 - m), e1 = __expf(v1 - m);
          float e2 = __expf(v2 - m), e3 = __expf(v3 - m);
          float s = e0 + e1 + e2 + e3;
          #pragma unroll
          for (int mm = 8; mm >= 1; mm >>= 1) s += __shfl_xor(s, mm, 64);
          float inv = 1.f / s;
          int prow = (l >> 4)*4 + r;
          int lo = l & 7, hb = (l >> 3) & 1, sw = prow & 7;
          Pl[wid*1024 + prow*64 + ((0 + hb) ^ sw)*8 + lo] = f2bf(e0 * inv);
          Pl[wid*1024 + prow*64 + ((2 + hb) ^ sw)*8 + lo] = f2bf(e1 * inv);
          Pl[wid*1024 + prow*64 + ((4 + hb) ^ sw)*8 + lo] = f2bf(e2 * inv);
          Pl[wid*1024 + prow*64 + ((6 + hb) ^ sw)*8 + lo] = f2bf(e3 * inv);
        }
        s16x8 pf[2];
        #pragma unroll
        for (int ks = 0; ks < 2; ++ks)
          pf[ks] = *(const s16x8*)&Pl[wid*1024 + (l & 15)*64 + ((ks*4 + (l >> 4)) ^ (l & 7))*8];
        f32x4 oc[4];
        #pragma unroll
        for (int ni = 0; ni < 4; ++ni) {
          f32x4 z; z[0]=0.f; z[1]=0.f; z[2]=0.f; z[3]=0.f;
          z = __builtin_amdgcn_mfma_f32_16x16x32_bf16(pf[0], vf[0][ni], z, 0, 0, 0);
          oc[ni] = __builtin_amdgcn_mfma_f32_16x16x32_bf16(pf[1], vf[1][ni], z, 0, 0, 0);
        }
        #pragma unroll
        for (int ni = 0; ni < 4; ++ni)
          #pragma unroll
          for (int r = 0; r < 4; ++r) {
            int grow = tm*256 + lr0 + (l >> 4)*4 + r;
            ap[(size_t)grow*ND + h*NHD + ni*16 + (l & 15)] = f2bf(oc[ni][r]);
          }
      }
      __syncthreads();   // Qs reads done before next hg overwrites
    }
  }
}

extern "C" void kernel_launch(void* const* d_in, const int* in_sizes, int n_in,
                              void* d_out, int out_size, void* d_ws, size_t ws_size,
                              hipStream_t stream) {
  (void)in_sizes; (void)n_in; (void)out_size; (void)ws_size;
  const float* x  = (const float*)d_in[0];
  const float* Wq = (const float*)d_in[1];
  const float* Wk = (const float*)d_in[2];
  const float* Wv = (const float*)d_in[3];
  const float* Wo = (const float*)d_in[4];
  const float* wscore = (const float*)d_in[5];

  char* base = (char*)d_ws;
  ushort* xb     = (ushort*)(base + 0);           // 64 MiB
  ushort* aout   = (ushort*)(base + 67108864);    // 64 MiB (attn out, token-major)
  float*  scores = (float*) (base + 134217728);   // 2 MiB
  ushort* uhi    = (ushort*)(base + 136314880);   // 32 KiB
  ushort* ulo    = (ushort*)(base + 136347648);   // 32 KiB
  ushort* wqb    = (ushort*)(base + 136380416);   // 2 MiB
  ushort* wkb    = (ushort*)(base + 138477568);   // 2 MiB
  ushort* wvb    = (ushort*)(base + 140574720);   // 2 MiB
  ushort* wob    = (ushort*)(base + 142671872);   // 2 MiB
  ushort* ksp    = (ushort*)(base + 144785408);   // 512 KiB
  ushort* vtsp   = (ushort*)(base + 145309696);   // 512 KiB

  convert_w_kernel<<<dim3(4096), dim3(256), 0, stream>>>(
      Wq, Wk, Wv, Wo, wscore, wqb, wkb, wvb, wob, uhi, ulo);
  prep_x_kernel<<<dim3(1024), dim3(256), 0, stream>>>(x, uhi, ulo, xb, scores);
  topsel_kv_kernel<<<dim3(64), dim3(256), 0, stream>>>(scores, xb, wkb, wvb, ksp, vtsp);
  gemm8_kernel<1><<<dim3(512), dim3(512), 0, stream>>>(xb, wqb, (void*)aout, ksp, vtsp);
  gemm8_kernel<0><<<dim3(512), dim3(512), 0, stream>>>(aout, wob, d_out, nullptr, nullptr);
}

// Round 21
// 263.051 us; speedup vs baseline: 1.3257x; 1.3257x over previous
//
#include <hip/hip_runtime.h>
#include <hip/hip_bf16.h>
#include <stdint.h>

#define NB 4
#define NT 8192
#define ND 1024
#define NH 16
#define NHD 64
#define NK 64        // top-k
#define NM (NB*NT)   // 32768

typedef __attribute__((ext_vector_type(4))) float f32x4;
typedef __attribute__((ext_vector_type(8))) short s16x8;
typedef const void __attribute__((address_space(1)))* gas1_t;
typedef void __attribute__((address_space(3)))* las3_t;

__device__ __forceinline__ float bf2f(ushort u) {
  union { uint32_t i; float f; } v; v.i = ((uint32_t)u) << 16; return v.f;
}
__device__ __forceinline__ ushort f2bf(float f) {
  union { float f; uint32_t i; } v; v.f = f;
  uint32_t r = v.i + 0x7FFFu + ((v.i >> 16) & 1u);
  return (ushort)(r >> 16);
}
__device__ __forceinline__ uint32_t f2ord(uint32_t u) {
  return (u & 0x80000000u) ? ~u : (u | 0x80000000u);
}

// ---- convert weights to bf16; blocks 0..63 also compute u (split-bf16) ----
__global__ __launch_bounds__(256) void convert_w_kernel(
    const float* __restrict__ Wq, const float* __restrict__ Wk,
    const float* __restrict__ Wv, const float* __restrict__ Wo,
    const float* __restrict__ wscore,
    ushort* __restrict__ wqb, ushort* __restrict__ wkb,
    ushort* __restrict__ wvb, ushort* __restrict__ wob,
    ushort* __restrict__ uhi, ushort* __restrict__ ulo) {
  int i = blockIdx.x * 256 + threadIdx.x;   // grid covers exactly 1M
  wqb[i] = f2bf(Wq[i]); wkb[i] = f2bf(Wk[i]);
  wvb[i] = f2bf(Wv[i]); wob[i] = f2bf(Wo[i]);
  if (blockIdx.x < 64) {   // fused prep_u: u[h] = sum_d wscore[d]*Wk[h*64+d]
    int e = (blockIdx.x & 3) * 256 + threadIdx.x;
    int h = blockIdx.x >> 2;
    float acc = 0.f;
    #pragma unroll 8
    for (int d = 0; d < NHD; ++d) acc += wscore[d] * Wk[(size_t)(h*NHD + d)*ND + e];
    ushort hv = f2bf(acc);
    uhi[h*ND + e] = hv;
    ulo[h*ND + e] = f2bf(acc - bf2f(hv));
  }
}

// ---- x -> xb (bf16) fused with scores = x @ u^T via split-bf16 MFMA ----
__global__ __launch_bounds__(256) void prep_x_kernel(
    const float* __restrict__ x, const ushort* __restrict__ uhi,
    const ushort* __restrict__ ulo, ushort* __restrict__ xb,
    float* __restrict__ scores) {
  __shared__ __align__(16) ushort Ahi[32 * 128];
  __shared__ __align__(16) ushort Alo[32 * 128];
  __shared__ float red[4][2][16][17];
  int t = threadIdx.x, w = t >> 6, l = t & 63;
  int tok0 = blockIdx.x * 32;
  int srow = t >> 3;             // stage row 0..31
  int sg = (t & 7) * 2;          // stage granule base (2 granules of 8 bf16)
  int rs = l & 15, ks8 = (l >> 4) * 8;
  f32x4 acc[2];
  acc[0] = (f32x4){0.f,0.f,0.f,0.f};
  acc[1] = (f32x4){0.f,0.f,0.f,0.f};
  for (int kc = 0; kc < 8; ++kc) {
    int kb = kc * 128;
    {  // coalesced stage: x[tok0+srow][kb + sg*8 .. +16]
      const float* xr = x + (size_t)(tok0 + srow) * ND + kb + sg * 8;
      f32x4 v0 = *(const f32x4*)xr;
      f32x4 v1 = *(const f32x4*)(xr + 4);
      f32x4 v2 = *(const f32x4*)(xr + 8);
      f32x4 v3 = *(const f32x4*)(xr + 12);
      s16x8 hi0, lo0, hi1, lo1;
      #pragma unroll
      for (int j = 0; j < 4; ++j) {
        ushort h;
        h = f2bf(v0[j]); hi0[j]   = (short)h; lo0[j]   = (short)f2bf(v0[j] - bf2f(h));
        h = f2bf(v1[j]); hi0[4+j] = (short)h; lo0[4+j] = (short)f2bf(v1[j] - bf2f(h));
        h = f2bf(v2[j]); hi1[j]   = (short)h; lo1[j]   = (short)f2bf(v2[j] - bf2f(h));
        h = f2bf(v3[j]); hi1[4+j] = (short)h; lo1[4+j] = (short)f2bf(v3[j] - bf2f(h));
      }
      ushort* xo = xb + (size_t)(tok0 + srow) * ND + kb + sg * 8;
      *(s16x8*)xo = hi0;              // coalesced 32B/thread
      *(s16x8*)(xo + 8) = hi1;
      int p0 = (sg ^ (srow & 7)) * 8, p1 = ((sg + 1) ^ (srow & 7)) * 8;
      *(s16x8*)&Ahi[srow*128 + p0] = hi0;
      *(s16x8*)&Ahi[srow*128 + p1] = hi1;
      *(s16x8*)&Alo[srow*128 + p0] = lo0;
      *(s16x8*)&Alo[srow*128 + p1] = lo1;
    }
    __syncthreads();
    {  // wave w consumes cols [w*32, w*32+32) of this 128-col step
      s16x8 bh = *(const s16x8*)(uhi + rs * ND + kb + w * 32 + ks8);
      s16x8 bl = *(const s16x8*)(ulo + rs * ND + kb + w * 32 + ks8);
      int gl = w * 4 + (l >> 4);
      #pragma unroll
      for (int mi = 0; mi < 2; ++mi) {
        int row = mi * 16 + rs;
        int gp = (gl ^ (row & 7)) * 8;
        s16x8 ah = *(const s16x8*)&Ahi[row*128 + gp];
        s16x8 al = *(const s16x8*)&Alo[row*128 + gp];
        acc[mi] = __builtin_amdgcn_mfma_f32_16x16x32_bf16(ah, bh, acc[mi], 0, 0, 0);
        acc[mi] = __builtin_amdgcn_mfma_f32_16x16x32_bf16(al, bh, acc[mi], 0, 0, 0);
        acc[mi] = __builtin_amdgcn_mfma_f32_16x16x32_bf16(ah, bl, acc[mi], 0, 0, 0);
      }
    }
    __syncthreads();
  }
  #pragma unroll
  for (int mi = 0; mi < 2; ++mi)
    #pragma unroll
    for (int r = 0; r < 4; ++r)
      red[w][mi][(l >> 4) * 4 + r][l & 15] = acc[mi][r];
  __syncthreads();
  int boff = ((tok0 >> 13) << 4);
  int tt0 = tok0 & (NT - 1);
  #pragma unroll
  for (int it = 0; it < 2; ++it) {
    int tok = t & 31, h = (t >> 5) + it * 8;
    int mi = tok >> 4, row = tok & 15;
    float s = red[0][mi][row][h] + red[1][mi][row][h]
            + red[2][mi][row][h] + red[3][mi][row][h];
    scores[(size_t)(boff + h) * NT + tt0 + tok] = s;
  }
}

// ---- FUSED: top-64 radix-select (kid in LDS) + MFMA K/V projection ----
__global__ __launch_bounds__(256) void topsel_kv_kernel(
    const float* __restrict__ scores, const ushort* __restrict__ xb,
    const ushort* __restrict__ wkb, const ushort* __restrict__ wvb,
    ushort* __restrict__ ksp, ushort* __restrict__ vtsp) {
  int bh = blockIdx.x, t = threadIdx.x;
  int b = bh >> 4, h = bh & 15;
  __shared__ uint32_t keys[NT];      // 32 KiB
  __shared__ int hist[4096];         // 16 KiB
  __shared__ uint32_t ck[512];
  __shared__ int ci[512];
  __shared__ int chunksum[256];
  __shared__ int s_binB, s_c0;
  __shared__ int cnt_hi, cnt_cand;
  __shared__ int kid[64];
  __shared__ __align__(16) ushort Xs[64 * 128];     // 16 KiB
  __shared__ __align__(16) ushort Ws[2][64 * 128];  // 32 KiB

  // ---- phase 1: top-64 ----
  for (int i = t; i < 4096; i += 256) hist[i] = 0;
  if (t == 0) { cnt_hi = 0; cnt_cand = 0; }
  __syncthreads();
  const uint4* sg = (const uint4*)(scores + (size_t)bh * NT);
  for (int i = t; i < NT/4; i += 256) {
    uint4 v = sg[i];
    uint32_t k0 = f2ord(v.x), k1 = f2ord(v.y), k2 = f2ord(v.z), k3 = f2ord(v.w);
    keys[i*4+0] = k0; keys[i*4+1] = k1; keys[i*4+2] = k2; keys[i*4+3] = k3;
    atomicAdd(&hist[k0 >> 20], 1); atomicAdd(&hist[k1 >> 20], 1);
    atomicAdd(&hist[k2 >> 20], 1); atomicAdd(&hist[k3 >> 20], 1);
  }
  __syncthreads();
  {
    int hi = 4095 - t * 16;
    int s = 0;
    #pragma unroll
    for (int j = 0; j < 16; ++j) s += hist[hi - j];
    chunksum[t] = s;
  }
  __syncthreads();
  if (t == 0) {
    int cum = 0, c = 0;
    while (cum + chunksum[c] < NK) { cum += chunksum[c]; ++c; }
    int bin = 4095 - c * 16;
    while (cum + hist[bin] < NK) { cum += hist[bin]; --bin; }
    s_binB = bin; s_c0 = cum;
  }
  __syncthreads();
  int binB = s_binB, c0 = s_c0;
  for (int i = t; i < NT; i += 256) {
    int bb = keys[i] >> 20;
    if (bb > binB) {
      int p = atomicAdd(&cnt_hi, 1);
      kid[p] = i;
    } else if (bb == binB) {
      int p = atomicAdd(&cnt_cand, 1);
      if (p < 512) { ck[p] = keys[i]; ci[p] = i; }
    }
  }
  __syncthreads();
  int nc = cnt_cand; if (nc > 512) nc = 512;
  int need = NK - c0;
  for (int p = t; p < nc; p += 256) {
    uint32_t myk = ck[p]; int myi = ci[p];
    int rank = 0;
    for (int j = 0; j < nc; ++j) {
      uint32_t kj = ck[j];
      rank += (kj > myk || (kj == myk && ci[j] < myi)) ? 1 : 0;
    }
    if (rank < need) kid[c0 + rank] = myi;
  }

  // ---- phase 2: K_sp = X_sel @ Wk_h^T, V_sp^T likewise (MFMA) ----
  int w = t >> 6, l = t & 63;
  int sel = w >> 1, nb = (w & 1) * 32;
  f32x4 acc[4][2];
  #pragma unroll
  for (int mi = 0; mi < 4; ++mi)
    #pragma unroll
    for (int ni = 0; ni < 2; ++ni) acc[mi][ni] = (f32x4){0.f,0.f,0.f,0.f};
  int srow = t >> 2;             // 0..63
  int gj = (t & 3) * 4;          // granule base
  for (int kc = 0; kc < ND; kc += 128) {
    __syncthreads();
    const ushort* xr  = xb  + (size_t)(b*NT + kid[srow]) * ND + kc;
    const ushort* wkr = wkb + (size_t)(h*NHD + srow) * ND + kc;
    const ushort* wvr = wvb + (size_t)(h*NHD + srow) * ND + kc;
    #pragma unroll
    for (int j = 0; j < 4; ++j) {
      int p = ((gj + j) ^ (srow & 7)) * 8;
      *(uint4*)&Xs[srow*128 + p]    = *(const uint4*)(xr  + (gj + j) * 8);
      *(uint4*)&Ws[0][srow*128 + p] = *(const uint4*)(wkr + (gj + j) * 8);
      *(uint4*)&Ws[1][srow*128 + p] = *(const uint4*)(wvr + (gj + j) * 8);
    }
    __syncthreads();
    #pragma unroll
    for (int ks = 0; ks < 4; ++ks) {
      s16x8 bfr[2], afr[4];
      #pragma unroll
      for (int ni = 0; ni < 2; ++ni) {
        int row = nb + ni*16 + (l & 15);
        bfr[ni] = *(const s16x8*)&Ws[sel][row*128 + ((ks*4 + (l >> 4)) ^ (row & 7))*8];
      }
      #pragma unroll
      for (int mi = 0; mi < 4; ++mi) {
        int row = mi*16 + (l & 15);
        afr[mi] = *(const s16x8*)&Xs[row*128 + ((ks*4 + (l >> 4)) ^ (row & 7))*8];
      }
      #pragma unroll
      for (int mi = 0; mi < 4; ++mi)
        #pragma unroll
        for (int ni = 0; ni < 2; ++ni)
          acc[mi][ni] = __builtin_amdgcn_mfma_f32_16x16x32_bf16(
              afr[mi], bfr[ni], acc[mi][ni], 0, 0, 0);
    }
  }
  // epilogue: C row = key = mi*16+(l>>4)*4+r, col = d = nb+ni*16+(l&15)
  #pragma unroll
  for (int mi = 0; mi < 4; ++mi)
    #pragma unroll
    for (int ni = 0; ni < 2; ++ni) {
      int d = nb + ni*16 + (l & 15);
      int key0 = mi*16 + (l >> 4)*4;
      if (sel == 0) {
        #pragma unroll
        for (int r = 0; r < 4; ++r)
          ksp[((size_t)bh*NK + key0 + r)*NHD + d] = f2bf(acc[mi][ni][r]);
      } else {
        ushort4 o;
        o.x = f2bf(acc[mi][ni][0]); o.y = f2bf(acc[mi][ni][1]);
        o.z = f2bf(acc[mi][ni][2]); o.w = f2bf(acc[mi][ni][3]);
        *(ushort4*)&vtsp[((size_t)bh*NHD + d)*NK + key0] = o;
      }
    }
}

// ==== 256x256 GEMM, 8 kh-split phases/K-tile (R11 known-good, ~73us) ====
template<int STORE_BF16>
__global__ __launch_bounds__(512, 2) void gemm8_kernel(
    const ushort* __restrict__ A, const ushort* __restrict__ Bw,
    void* __restrict__ Cout) {
  __shared__ __align__(16) char lds[131072];
  const int t = threadIdx.x, wid = t >> 6, l = t & 63;
  const int wr = wid >> 2, wc = wid & 3;
  int bid = blockIdx.x;                  // nwg = 512 = 8 XCD * 64
  int wg = (bid & 7) * 64 + (bid >> 3);  // XCD swizzle (bijective, 512%8==0)
  int tm = wg >> 2, tn = wg & 3;
  const int K = 1024, N = 1024;
  const ushort* Ab = A + (size_t)tm * 256 * K;
  const ushort* Bb = Bw + (size_t)tn * 256 * K;
  const int skh  = ((l & 3) * 8) ^ (((l >> 5) & 1) << 4);  // pre-swizzled src k
  const int srow = l >> 2;
  const int lane_off = (l & 15) * 64 + ((((l >> 4) * 8) ^ (((l >> 3) & 1) << 4)) * 2);
  f32x4 acc[8][4];
  #pragma unroll
  for (int i = 0; i < 8; ++i)
    #pragma unroll
    for (int j = 0; j < 4; ++j) acc[i][j] = (f32x4){0.f, 0.f, 0.f, 0.f};
  s16x8 afr[4][2], bfr[2][2];

#define STG(gbase, matoff, half, ktile, buf) do { \
    const ushort* _s = (gbase) + (size_t)((half)*128 + wid*16 + srow) * K + (ktile)*64 + skh; \
    int _d = (buf)*65536 + (matoff) + ((half)*128 + wid*16)*64; \
    __builtin_amdgcn_global_load_lds((gas1_t)_s, (las3_t)(lds + _d), 16, 0, 0); \
    __builtin_amdgcn_global_load_lds((gas1_t)(_s + 32), (las3_t)(lds + _d + 16384), 16, 0, 0); \
  } while (0)

#define RD_A(mh, kh, buf) do { \
    _Pragma("unroll") \
    for (int mi = 0; mi < 4; ++mi) \
      afr[mi][kh] = *(const s16x8*)(lds + (buf)*65536 + (kh)*16384 + \
                      ((((mh)*2 + wr)*64 + mi*16))*64 + lane_off); \
  } while (0)

#define RD_B(nh, kh, buf) do { \
    _Pragma("unroll") \
    for (int ni = 0; ni < 2; ++ni) \
      bfr[ni][kh] = *(const s16x8*)(lds + (buf)*65536 + 32768 + (kh)*16384 + \
                      (((nh)*128 + wc*32 + ni*16))*64 + lane_off); \
  } while (0)

#define MMAQH(mh, nh, kh) do { \
    __builtin_amdgcn_s_setprio(1); \
    _Pragma("unroll") \
    for (int mi = 0; mi < 4; ++mi) \
      _Pragma("unroll") \
      for (int ni = 0; ni < 2; ++ni) \
        acc[(mh)*4+mi][(nh)*2+ni] = __builtin_amdgcn_mfma_f32_16x16x32_bf16( \
            afr[mi][kh], bfr[ni][kh], acc[(mh)*4+mi][(nh)*2+ni], 0, 0, 0); \
    __builtin_amdgcn_s_setprio(0); \
  } while (0)

#define LG0() do { asm volatile("s_waitcnt lgkmcnt(0)" ::: "memory"); \
                   __builtin_amdgcn_sched_barrier(0); } while (0)
#define ENDPH() do { __builtin_amdgcn_sched_barrier(0); \
                     __builtin_amdgcn_s_barrier(); } while (0)

#define TILE(kt, bc, bn) do { \
  LG0(); MMAQH(0,0,0); RD_A(0,1,bc); RD_B(0,1,bc); ENDPH(); \
  LG0(); MMAQH(0,0,1); RD_B(1,0,bc); \
  if ((kt)+1 < 16) STG(Bb,32768,0,(kt)+1,bn); ENDPH(); \
  LG0(); MMAQH(0,1,0); RD_B(1,1,bc); ENDPH(); \
  LG0(); MMAQH(0,1,1); RD_A(1,0,bc); \
  if ((kt)+2 < 16) STG(Ab,0,0,(kt)+2,bc); ENDPH(); \
  LG0(); MMAQH(1,1,0); RD_A(1,1,bc); ENDPH(); \
  LG0(); MMAQH(1,1,1); RD_B(0,0,bc); \
  if ((kt)+2 < 16) STG(Bb,32768,1,(kt)+2,bc); ENDPH(); \
  LG0(); MMAQH(1,0,0); RD_B(0,1,bc); ENDPH(); \
  LG0(); MMAQH(1,0,1); \
  if ((kt) < 14)       { asm volatile("s_waitcnt vmcnt(4)" ::: "memory"); } \
  else if ((kt) == 14) { asm volatile("s_waitcnt vmcnt(0)" ::: "memory"); } \
  __builtin_amdgcn_sched_barrier(0); \
  __builtin_amdgcn_s_barrier(); \
  if ((kt)+1 < 16) { RD_A(0,0,bn); RD_B(0,0,bn); } \
  if ((kt)+2 < 16) STG(Ab,0,1,(kt)+2,bc); \
} while (0)

  // prologue: t0 all 4 halves + t1 {A0,B1,A1}; B0(t1) arrives at ph2 of t0
  STG(Ab,0,0,0,0); STG(Bb,32768,0,0,0); STG(Ab,0,1,0,0); STG(Bb,32768,1,0,0);
  STG(Ab,0,0,1,1); STG(Bb,32768,1,1,1); STG(Ab,0,1,1,1);
  asm volatile("s_waitcnt vmcnt(6)" ::: "memory");   // t0's 8 loads done
  __builtin_amdgcn_s_barrier();
  RD_A(0,0,0); RD_B(0,0,0);                          // A0k0,B0k0 of t0

  for (int k2 = 0; k2 < 8; ++k2) {
    TILE(2*k2,     0, 1);
    TILE(2*k2 + 1, 1, 0);
  }
#undef TILE
#undef STG
#undef RD_A
#undef RD_B
#undef MMAQH
#undef LG0
#undef ENDPH

  // epilogue: C/D layout col=l&15, row=(l>>4)*4+r
  #pragma unroll
  for (int mi8 = 0; mi8 < 8; ++mi8) {
    int grow = tm*256 + (((mi8 >> 2)*2 + wr)*64) + (mi8 & 3)*16 + (l >> 4)*4;
    #pragma unroll
    for (int ni4 = 0; ni4 < 4; ++ni4) {
      int gcol = tn*256 + (ni4 >> 1)*128 + wc*32 + (ni4 & 1)*16 + (l & 15);
      #pragma unroll
      for (int r = 0; r < 4; ++r) {
        size_t off = (size_t)(grow + r) * N + gcol;
        if (STORE_BF16) ((ushort*)Cout)[off] = f2bf(acc[mi8][ni4][r]);
        else            ((float*)Cout)[off]  = acc[mi8][ni4][r];
      }
    }
  }
}

// ---- attention vs 64 keys: per-wave 64 q-rows; K/V frags live in registers ----
__global__ __launch_bounds__(256, 2) void attn_kernel(
    const ushort* __restrict__ qg, const ushort* __restrict__ ksp,
    const ushort* __restrict__ vtsp, ushort* __restrict__ aout) {
  int bh = blockIdx.y;
  int b = bh >> 4, h = bh & 15;
  int t = threadIdx.x, w = t >> 6, l = t & 63;
  __shared__ __align__(16) ushort Pl[4][1024];
  const ushort* kb = ksp + (size_t)bh * NK * NHD;
  const ushort* vb = vtsp + (size_t)bh * NHD * NK;
  s16x8 kf[2][4], vf[2][4];
  #pragma unroll
  for (int ks = 0; ks < 2; ++ks)
    #pragma unroll
    for (int ni = 0; ni < 4; ++ni) {
      kf[ks][ni] = *(const s16x8*)&kb[(size_t)(ni*16 + (l & 15))*NHD + ks*32 + (l >> 4)*8];
      vf[ks][ni] = *(const s16x8*)&vb[(size_t)(ni*16 + (l & 15))*NK + ks*32 + (l >> 4)*8];
    }
  int rowbase = blockIdx.x * 256 + w * 64;
  #pragma unroll 1
  for (int mi = 0; mi < 4; ++mi) {
    int r0 = rowbase + mi * 16;
    s16x8 af[2];
    #pragma unroll
    for (int ks = 0; ks < 2; ++ks)
      af[ks] = *(const s16x8*)&qg[(size_t)(b*NT + r0 + (l & 15))*ND + h*NHD + ks*32 + (l >> 4)*8];
    f32x4 sc[4];
    #pragma unroll
    for (int ni = 0; ni < 4; ++ni) {
      f32x4 z; z[0]=0.f; z[1]=0.f; z[2]=0.f; z[3]=0.f;
      z = __builtin_amdgcn_mfma_f32_16x16x32_bf16(af[0], kf[0][ni], z, 0, 0, 0);
      sc[ni] = __builtin_amdgcn_mfma_f32_16x16x32_bf16(af[1], kf[1][ni], z, 0, 0, 0);
    }
    #pragma unroll
    for (int r = 0; r < 4; ++r) {
      float v0 = sc[0][r]*0.125f, v1 = sc[1][r]*0.125f;
      float v2 = sc[2][r]*0.125f, v3 = sc[3][r]*0.125f;
      float m = fmaxf(fmaxf(v0, v1), fmaxf(v2, v3));
      #pragma unroll
      for (int mm = 8; mm >= 1; mm >>= 1) m = fmaxf(m, __shfl_xor(m, mm, 64));
      float e0 = __expf(v0 - m), e1 = __expf(v1 - m);
      float e2 = __expf(v2 - m), e3 = __expf(v3 - m);
      float s = e0 + e1 + e2 + e3;
      #pragma unroll
      for (int mm = 8; mm >= 1; mm >>= 1) s += __shfl_xor(s, mm, 64);
      float inv = 1.f / s;
      int prow = (l >> 4)*4 + r;
      int lo = l & 7, hb = (l >> 3) & 1, sw = prow & 7;
      Pl[w][prow*64 + ((0 + hb) ^ sw)*8 + lo] = f2bf(e0 * inv);
      Pl[w][prow*64 + ((2 + hb) ^ sw)*8 + lo] = f2bf(e1 * inv);
      Pl[w][prow*64 + ((4 + hb) ^ sw)*8 + lo] = f2bf(e2 * inv);
      Pl[w][prow*64 + ((6 + hb) ^ sw)*8 + lo] = f2bf(e3 * inv);
    }
    s16x8 pf[2];
    #pragma unroll
    for (int ks = 0; ks < 2; ++ks)
      pf[ks] = *(const s16x8*)&Pl[w][(l & 15)*64 + ((ks*4 + (l >> 4)) ^ (l & 7))*8];
    f32x4 oc[4];
    #pragma unroll
    for (int ni = 0; ni < 4; ++ni) {
      f32x4 z; z[0]=0.f; z[1]=0.f; z[2]=0.f; z[3]=0.f;
      z = __builtin_amdgcn_mfma_f32_16x16x32_bf16(pf[0], vf[0][ni], z, 0, 0, 0);
      oc[ni] = __builtin_amdgcn_mfma_f32_16x16x32_bf16(pf[1], vf[1][ni], z, 0, 0, 0);
    }
    #pragma unroll
    for (int ni = 0; ni < 4; ++ni)
      #pragma unroll
      for (int r = 0; r < 4; ++r) {
        int row = r0 + (l >> 4)*4 + r;
        aout[(size_t)(b*NT + row)*ND + h*NHD + ni*16 + (l & 15)] = f2bf(oc[ni][r]);
      }
  }
}

extern "C" void kernel_launch(void* const* d_in, const int* in_sizes, int n_in,
                              void* d_out, int out_size, void* d_ws, size_t ws_size,
                              hipStream_t stream) {
  (void)in_sizes; (void)n_in; (void)out_size; (void)ws_size;
  const float* x  = (const float*)d_in[0];
  const float* Wq = (const float*)d_in[1];
  const float* Wk = (const float*)d_in[2];
  const float* Wv = (const float*)d_in[3];
  const float* Wo = (const float*)d_in[4];
  const float* wscore = (const float*)d_in[5];

  char* base = (char*)d_ws;
  ushort* xb     = (ushort*)(base + 0);           // 64 MiB  (reused as attn out)
  ushort* qb     = (ushort*)(base + 67108864);    // 64 MiB
  float*  scores = (float*) (base + 134217728);   // 2 MiB
  ushort* uhi    = (ushort*)(base + 136314880);   // 32 KiB
  ushort* ulo    = (ushort*)(base + 136347648);   // 32 KiB
  ushort* wqb    = (ushort*)(base + 136380416);   // 2 MiB
  ushort* wkb    = (ushort*)(base + 138477568);   // 2 MiB
  ushort* wvb    = (ushort*)(base + 140574720);   // 2 MiB
  ushort* wob    = (ushort*)(base + 142671872);   // 2 MiB
  ushort* ksp    = (ushort*)(base + 144785408);   // 512 KiB
  ushort* vtsp   = (ushort*)(base + 145309696);   // 512 KiB
  ushort* aout   = xb;   // xb is dead after gemm_q + topsel_kv

  convert_w_kernel<<<dim3(4096), dim3(256), 0, stream>>>(
      Wq, Wk, Wv, Wo, wscore, wqb, wkb, wvb, wob, uhi, ulo);
  prep_x_kernel<<<dim3(1024), dim3(256), 0, stream>>>(x, uhi, ulo, xb, scores);
  topsel_kv_kernel<<<dim3(64), dim3(256), 0, stream>>>(scores, xb, wkb, wvb, ksp, vtsp);
  gemm8_kernel<1><<<dim3(512), dim3(512), 0, stream>>>(xb, wqb, (void*)qb);
  attn_kernel<<<dim3(32, 64), dim3(256), 0, stream>>>(qb, ksp, vtsp, aout);
  gemm8_kernel<0><<<dim3(512), dim3(512), 0, stream>>>(aout, wob, d_out);
}